// Round 8
// baseline (123.014 us; speedup 1.0000x reference)
//
#include <hip/hip_runtime.h>
#include <hip/hip_bf16.h>
#include <stdint.h>

#define D_MODEL 1024
#define NHEADS  16
#define HDIM    64
#define BATCH   2
#define SEQ     2048
#define MROWS   (BATCH*SEQ)   // 4096

typedef __attribute__((ext_vector_type(8))) short  bf16x8;
typedef __attribute__((ext_vector_type(4))) float  f32x4;
typedef __attribute__((ext_vector_type(4))) int    int4v;

__device__ __forceinline__ unsigned short f2bf(float f) {
  unsigned int u = __float_as_uint(f);
  u = (u + 0x7fffu + ((u >> 16) & 1u)) >> 16;   // RNE
  return (unsigned short)u;
}

__device__ __forceinline__ unsigned cvtpk_bf16(float lo, float hi) {
  unsigned r;
  asm("v_cvt_pk_bf16_f32 %0, %1, %2" : "=v"(r) : "v"(lo), "v"(hi));
  return r;
}

__device__ __forceinline__ int4v pack8(const float4& x, const float4& y) {
  int4v r;
  r[0] = (int)cvtpk_bf16(x.x, x.y);
  r[1] = (int)cvtpk_bf16(x.z, x.w);
  r[2] = (int)cvtpk_bf16(y.x, y.y);
  r[3] = (int)cvtpk_bf16(y.z, y.w);
  return r;
}

__device__ __forceinline__ void gload_lds16(const unsigned short* g, unsigned short* l) {
  __builtin_amdgcn_global_load_lds(
      (const __attribute__((address_space(1))) void*)g,
      (__attribute__((address_space(3))) void*)l,
      16, 0, 0);
}

// chunk swizzles
__device__ __forceinline__ int swz_chunk(int row) { return (row + (row >> 3)) & 7; }  // 128B rows
__device__ __forceinline__ int swz4(int row) { return (row + (row >> 2)) & 3; }       // 64B rows
// K-row permutation for attn zero-shuffle P
__device__ __forceinline__ int kperm(int m) {
  return (m & 0x63) | ((m & 0x10) >> 2) | ((m & 0x0C) << 1);
}

// ---------------------------------------------------------------- QKV projection
// 256x256 tile, 8 waves, BK=32, double-buffer, f32 inputs reg-staged (T14 split:
// issue loads early, cvt+ds_write after compute, ONE barrier per K-tile).
// z==0: Q (scaled), z==1: K, z==2: V written TRANSPOSED to [B,H,Dh,S].
__global__ __launch_bounds__(512, 1) void gemm_qkv256(
    const float* __restrict__ Xq, const float* __restrict__ Xk,
    const float* __restrict__ Xv,
    const float* __restrict__ Wq, const float* __restrict__ Wk,
    const float* __restrict__ Wv,
    const float* __restrict__ bq, const float* __restrict__ bk,
    const float* __restrict__ bv,
    unsigned short* __restrict__ oq, unsigned short* __restrict__ ok,
    unsigned short* __restrict__ ov) {
  __shared__ __align__(16) unsigned short LDS[2 * 16384];   // [buf][A 8K | B 8K elems]

  const int tid  = threadIdx.x;
  const int lane = tid & 63;
  const int w8   = tid >> 6;
  const int wr   = w8 >> 2;         // 0..1 (128-row half)
  const int wc   = w8 & 3;          // 0..3 (64-col group)
  const int g    = lane >> 4;
  const int cl   = lane & 15;

  int fid = blockIdx.x;                       // 0..191
  int sid = (fid & 7) * 24 + (fid >> 3);      // XCD-contiguous
  int ny = sid / 12, nx = sid % 12;
  int z  = nx >> 2;
  int n0 = (nx & 3) * 256;
  int m0 = ny * 256;

  const float* X    = (z == 0) ? Xq : (z == 1) ? Xk : Xv;
  const float* W    = (z == 0) ? Wq : (z == 1) ? Wk : Wv;
  const float* bias = (z == 0) ? bq : (z == 1) ? bk : bv;
  float scale = (z == 0) ? 0.18033688011112042f : 1.0f;   // 1/8 * log2(e)

  // staging: thread -> row sr (0..255), col-half sh (16 elems). 4 float4 loads each side.
  const int sr  = tid >> 1;
  const int sh  = tid & 1;
  const int ssw = swz4(sr);
  const float* Xrow = X + (size_t)(m0 + sr) * D_MODEL + sh * 16;
  const float* Wrow = W + (size_t)(n0 + sr) * D_MODEL + sh * 16;
  const int wb0 = sr * 64 + (((2 * sh) ^ ssw) << 4);
  const int wb1 = sr * 64 + (((2 * sh + 1) ^ ssw) << 4);

  float4 rA[4], rB[4];
  auto load_t = [&](int t) {
    const float* pa = Xrow + t * 32;
    rA[0] = *(const float4*)(pa);     rA[1] = *(const float4*)(pa + 4);
    rA[2] = *(const float4*)(pa + 8); rA[3] = *(const float4*)(pa + 12);
    const float* pb = Wrow + t * 32;
    rB[0] = *(const float4*)(pb);     rB[1] = *(const float4*)(pb + 4);
    rB[2] = *(const float4*)(pb + 8); rB[3] = *(const float4*)(pb + 12);
  };
  auto write_t = [&](int bi) {
    char* A_ = (char*)(LDS + bi * 16384);
    char* B_ = A_ + 16384;            // 8192 elems = 16384 bytes
    *(int4v*)(A_ + wb0) = pack8(rA[0], rA[1]);
    *(int4v*)(A_ + wb1) = pack8(rA[2], rA[3]);
    *(int4v*)(B_ + wb0) = pack8(rB[0], rB[1]);
    *(int4v*)(B_ + wb1) = pack8(rB[2], rB[3]);
  };

  f32x4 acc[8][4] = {};

  load_t(0);
  write_t(0);
  __syncthreads();

#pragma unroll 2
  for (int t = 0; t < 32; ++t) {
    if (t < 31) load_t(t + 1);                 // issue next-tile loads early
    __builtin_amdgcn_sched_barrier(0);         // pin the prefetch issue point
    const char* Ab = (const char*)(LDS + (t & 1) * 16384);
    const char* Bb = Ab + 16384;
    bf16x8 af[4], bfr[4];
#pragma unroll
    for (int j = 0; j < 4; ++j) {
      int row = wc * 64 + j * 16 + cl;
      bfr[j] = *(const bf16x8*)(Bb + row * 64 + ((g ^ swz4(row)) << 4));
    }
#pragma unroll
    for (int i = 0; i < 4; ++i) {
      int row = wr * 128 + i * 16 + cl;
      af[i] = *(const bf16x8*)(Ab + row * 64 + ((g ^ swz4(row)) << 4));
    }
    __builtin_amdgcn_s_setprio(1);
#pragma unroll
    for (int i = 0; i < 4; ++i)
#pragma unroll
      for (int j = 0; j < 4; ++j)
        acc[i][j] = __builtin_amdgcn_mfma_f32_16x16x32_bf16(af[i], bfr[j],
                                                            acc[i][j], 0, 0, 0);
    __builtin_amdgcn_s_setprio(0);
#pragma unroll
    for (int i = 0; i < 4; ++i) {
      int row = wr * 128 + (4 + i) * 16 + cl;
      af[i] = *(const bf16x8*)(Ab + row * 64 + ((g ^ swz4(row)) << 4));
    }
    __builtin_amdgcn_s_setprio(1);
#pragma unroll
    for (int i = 0; i < 4; ++i)
#pragma unroll
      for (int j = 0; j < 4; ++j)
        acc[4 + i][j] = __builtin_amdgcn_mfma_f32_16x16x32_bf16(af[i], bfr[j],
                                                                acc[4 + i][j], 0, 0, 0);
    __builtin_amdgcn_s_setprio(0);
    if (t < 31) write_t((t + 1) & 1);          // cvt+ds_write after compute (loads landed)
    __syncthreads();                           // drains vmcnt+lgkm; next tile ready
  }

  if (z == 2) {
    // ---- V^T epilogue: vt[(b*1024 + n)][s], 4 r-contiguous s per 8B store
    int b = m0 >> 11;
    int sbase = (m0 & 2047) + wr * 128 + g * 4;
#pragma unroll
    for (int nj = 0; nj < 4; ++nj) {
      int n = n0 + wc * 64 + nj * 16 + cl;
      float bn = bias[n];
      unsigned short* vrow = ov + ((size_t)(b * 1024 + n)) * 2048;
#pragma unroll
      for (int mi = 0; mi < 8; ++mi) {
        int s = sbase + mi * 16;
        uint2 val;
        val.x = cvtpk_bf16(acc[mi][nj][0] + bn, acc[mi][nj][1] + bn);
        val.y = cvtpk_bf16(acc[mi][nj][2] + bn, acc[mi][nj][3] + bn);
        *(uint2*)(vrow + s) = val;
      }
    }
  } else {
    unsigned short* outp = (z == 0) ? oq : ok;
#pragma unroll
    for (int mi = 0; mi < 8; ++mi)
#pragma unroll
      for (int nj = 0; nj < 4; ++nj) {
        int n = n0 + wc * 64 + nj * 16 + cl;
        float bn = bias[n];
        int h = n >> 6, dh = n & 63;
#pragma unroll
        for (int r = 0; r < 4; ++r) {
          int m = m0 + wr * 128 + mi * 16 + g * 4 + r;
          float val = (acc[mi][nj][r] + bn) * scale;
          int b = m >> 11, s = m & 2047;
          outp[(((size_t)(b * NHEADS + h)) * SEQ + s) * HDIM + dh] = f2bf(val);
        }
      }
  }
}

// ---------------------------------------------------------------- output projection
// 128x128 tile, 8 waves, BK=32, double-buffer. A (ctx bf16) via global_load_lds
// issued a full K-tile early; B (Wo f32) reg-staged with cvt.
__global__ __launch_bounds__(512, 1) void gemm_out2(
    const unsigned short* __restrict__ Xc, const float* __restrict__ Wo,
    const float* __restrict__ bo, float* __restrict__ out) {
  __shared__ __align__(16) unsigned short LDS[2 * 8192];   // [buf][A 4K | B 4K elems]

  const int tid  = threadIdx.x;
  const int lane = tid & 63;
  const int w8   = tid >> 6;
  const int wr   = w8 >> 2;         // 0..1 (64-row half)
  const int wc   = w8 & 3;          // 0..3 (32-col group)
  const int g    = lane >> 4;
  const int cl   = lane & 15;

  int fid = blockIdx.x;                       // 0..255
  int sid = (fid & 7) * 32 + (fid >> 3);      // XCD-contiguous
  int m0 = (sid >> 3) * 128;
  int n0 = (sid & 7) * 128;

  // staging: thread -> row ar (0..127), slot as (0..3)
  const int ar  = tid >> 2;
  const int as  = tid & 3;
  const int asw = swz4(ar);
  const unsigned short* Arow = Xc + (size_t)(m0 + ar) * D_MODEL + (as ^ asw) * 8;
  const float*          Brow = Wo + (size_t)(n0 + ar) * D_MODEL + (as ^ asw) * 8;
  const int bwb = ar * 64 + (as << 4);        // linear dest slot (source pre-swizzled)

  float4 rB0, rB1;
  auto gloadA = [&](int t, int bi) {
    gload_lds16(Arow + t * 32, LDS + bi * 8192 + tid * 8);
  };
  auto loadB = [&](int t) {
    const float* p = Brow + t * 32;
    rB0 = *(const float4*)(p);
    rB1 = *(const float4*)(p + 4);
  };
  auto writeB = [&](int bi) {
    char* B_ = (char*)(LDS + bi * 8192) + 8192;
    *(int4v*)(B_ + bwb) = pack8(rB0, rB1);
  };

  f32x4 acc[4][2] = {};

  gloadA(0, 0); loadB(0); writeB(0);
  __syncthreads();

#pragma unroll 2
  for (int t = 0; t < 32; ++t) {
    if (t < 31) { gloadA(t + 1, (t + 1) & 1); loadB(t + 1); }
    __builtin_amdgcn_sched_barrier(0);
    const char* Ab = (const char*)(LDS + (t & 1) * 8192);
    const char* Bb = Ab + 8192;
    bf16x8 af[4], bfr[2];
#pragma unroll
    for (int j = 0; j < 2; ++j) {
      int row = wc * 32 + j * 16 + cl;
      bfr[j] = *(const bf16x8*)(Bb + row * 64 + ((g ^ swz4(row)) << 4));
    }
#pragma unroll
    for (int i = 0; i < 4; ++i) {
      int row = wr * 64 + i * 16 + cl;
      af[i] = *(const bf16x8*)(Ab + row * 64 + ((g ^ swz4(row)) << 4));
    }
    __builtin_amdgcn_s_setprio(1);
#pragma unroll
    for (int i = 0; i < 4; ++i)
#pragma unroll
      for (int j = 0; j < 2; ++j)
        acc[i][j] = __builtin_amdgcn_mfma_f32_16x16x32_bf16(af[i], bfr[j],
                                                            acc[i][j], 0, 0, 0);
    __builtin_amdgcn_s_setprio(0);
    if (t < 31) writeB((t + 1) & 1);
    __syncthreads();
  }

#pragma unroll
  for (int mi = 0; mi < 4; ++mi)
#pragma unroll
    for (int nj = 0; nj < 2; ++nj) {
      int n = n0 + wc * 32 + nj * 16 + cl;
      float bn = bo[n];
#pragma unroll
      for (int r = 0; r < 4; ++r) {
        int m = m0 + wr * 64 + mi * 16 + g * 4 + r;
        out[(size_t)m * D_MODEL + n] = acc[mi][nj][r] + bn;
      }
    }
}

// ---------------------------------------------------------------- flash attention
// grid (32,16): x=bh, y=q-tile. 4 waves x 32 q. KVBLK=128, swapped QK^T,
// zero-shuffle P, direct exp2 (no max; scale cancels), ones-column row-sum.
__global__ __launch_bounds__(256, 2) void attn(
    const unsigned short* __restrict__ q, const unsigned short* __restrict__ k,
    const unsigned short* __restrict__ vt, unsigned short* __restrict__ ctx) {
  __shared__ __align__(16) unsigned short K0[128 * 64], V0[64 * 128];
  __shared__ __align__(16) unsigned short K1[128 * 64], V1[64 * 128];

  const int tid  = threadIdx.x;
  const int lane = tid & 63;
  const int wv   = tid >> 6;
  const int g    = lane >> 4;
  const int cl   = lane & 15;

  const int bh = blockIdx.x;
  const int qt = blockIdx.y;

  const unsigned short* qb  = q  + (size_t)bh * SEQ * HDIM;
  const unsigned short* kb  = k  + (size_t)bh * SEQ * HDIM;
  const unsigned short* vbt = vt + (size_t)bh * HDIM * SEQ;

  bf16x8 qf[2][2];
  {
    int qbase = qt * 128 + wv * 32;
#pragma unroll
    for (int qh = 0; qh < 2; ++qh) {
      const unsigned short* qp = qb + (size_t)(qbase + qh * 16 + cl) * HDIM + 8 * g;
      qf[qh][0] = *(const bf16x8*)(qp);
      qf[qh][1] = *(const bf16x8*)(qp + 32);
    }
  }

  const int srowK = tid >> 3;
  const int swzK  = swz_chunk(srowK);
  const int vrow  = tid >> 4;
  const int swzV  = swz_chunk(vrow);
  const int ldst  = tid * 16;

  f32x4 acc0[4] = {}, acc1[4] = {};
  f32x4 accs0 = {}, accs1 = {};
  const int4v onesi = {0x3F803F80, 0x3F803F80, 0x3F803F80, 0x3F803F80};
  const bf16x8 onesb = __builtin_bit_cast(bf16x8, onesi);

  auto stageK_ = [&](int t, unsigned short* Kb) {
    const unsigned short* kt_ = kb + (size_t)t * 128 * HDIM;
#pragma unroll
    for (int c = 0; c < 4; ++c) {
      int row  = srowK + 32 * c;
      int col  = ((tid & 7) ^ swzK ^ ((c & 1) << 2)) * 8;
      gload_lds16(kt_ + (size_t)kperm(row) * HDIM + col,
                  (unsigned short*)((char*)Kb + ldst + c * 4096));
    }
  };
  auto stageV_ = [&](int t, unsigned short* Vb) {
    const unsigned short* vt_ = vbt + t * 128;
#pragma unroll
    for (int c = 0; c < 4; ++c) {
      int row = vrow + 16 * c;
      int sw  = (swzV + 2 * c) & 7;
      int col = (((tid & 7) ^ sw) | (tid & 8)) * 8;
      gload_lds16(vt_ + (size_t)row * SEQ + col,
                  (unsigned short*)((char*)Vb + ldst + c * 4096));
    }
  };

  f32x4 sc[8][2];

  auto qk = [&](const unsigned short* Kb) {
#pragma unroll
    for (int ni = 0; ni < 8; ++ni) { sc[ni][0] = f32x4{}; sc[ni][1] = f32x4{}; }
    __builtin_amdgcn_s_setprio(1);
#pragma unroll
    for (int kc = 0; kc < 2; ++kc)
#pragma unroll
      for (int ni = 0; ni < 8; ++ni) {
        int row  = ni * 16 + cl;
        int byte = row * 128 + (((kc * 4 + g) ^ swz_chunk(row)) << 4);
        bf16x8 kf = *(const bf16x8*)((const char*)Kb + byte);
        sc[ni][0] = __builtin_amdgcn_mfma_f32_16x16x32_bf16(kf, qf[0][kc], sc[ni][0], 0, 0, 0);
        sc[ni][1] = __builtin_amdgcn_mfma_f32_16x16x32_bf16(kf, qf[1][kc], sc[ni][1], 0, 0, 0);
      }
    __builtin_amdgcn_s_setprio(0);
  };

  auto smpack = [&](int4v (&pa0)[4], int4v (&pa1)[4]) {
#pragma unroll
    for (int qh = 0; qh < 2; ++qh)
#pragma unroll
      for (int ni = 0; ni < 8; ++ni)
#pragma unroll
        for (int r = 0; r < 4; ++r)
          sc[ni][qh][r] = __builtin_amdgcn_exp2f(sc[ni][qh][r]);
#pragma unroll
    for (int kcp = 0; kcp < 4; ++kcp) {
      pa0[kcp][0] = (int)cvtpk_bf16(sc[2 * kcp][0][0], sc[2 * kcp][0][1]);
      pa0[kcp][1] = (int)cvtpk_bf16(sc[2 * kcp][0][2], sc[2 * kcp][0][3]);
      pa0[kcp][2] = (int)cvtpk_bf16(sc[2 * kcp + 1][0][0], sc[2 * kcp + 1][0][1]);
      pa0[kcp][3] = (int)cvtpk_bf16(sc[2 * kcp + 1][0][2], sc[2 * kcp + 1][0][3]);
      pa1[kcp][0] = (int)cvtpk_bf16(sc[2 * kcp][1][0], sc[2 * kcp][1][1]);
      pa1[kcp][1] = (int)cvtpk_bf16(sc[2 * kcp][1][2], sc[2 * kcp][1][3]);
      pa1[kcp][2] = (int)cvtpk_bf16(sc[2 * kcp + 1][1][0], sc[2 * kcp + 1][1][1]);
      pa1[kcp][3] = (int)cvtpk_bf16(sc[2 * kcp + 1][1][2], sc[2 * kcp + 1][1][3]);
    }
  };

  auto pv = [&](const unsigned short* Vb, int4v (&pa0)[4], int4v (&pa1)[4]) {
    __builtin_amdgcn_s_setprio(1);
#pragma unroll
    for (int kcp = 0; kcp < 4; ++kcp) {
      bf16x8 a0 = __builtin_bit_cast(bf16x8, pa0[kcp]);
      bf16x8 a1 = __builtin_bit_cast(bf16x8, pa1[kcp]);
#pragma unroll
      for (int nd = 0; nd < 4; ++nd) {
        int row = nd * 16 + cl;
        int c   = kcp * 4 + g;
        int byte = row * 256 + ((((c & 7) ^ swz_chunk(row)) | (c & 8)) << 4);
        bf16x8 vf = *(const bf16x8*)((const char*)Vb + byte);
        acc0[nd] = __builtin_amdgcn_mfma_f32_16x16x32_bf16(a0, vf, acc0[nd], 0, 0, 0);
        acc1[nd] = __builtin_amdgcn_mfma_f32_16x16x32_bf16(a1, vf, acc1[nd], 0, 0, 0);
      }
      accs0 = __builtin_amdgcn_mfma_f32_16x16x32_bf16(a0, onesb, accs0, 0, 0, 0);
      accs1 = __builtin_amdgcn_mfma_f32_16x16x32_bf16(a1, onesb, accs1, 0, 0, 0);
    }
    __builtin_amdgcn_s_setprio(0);
  };

  const int NT = SEQ / 128;   // 16
  stageK_(0, K0);
  stageV_(0, V0);
  __syncthreads();
  stageK_(1, K1);
  qk(K0);
  for (int i = 0; i < NT; ++i) {
    int4v pa0[4], pa1[4];
    smpack(pa0, pa1);
    __syncthreads();
    if (i + 2 < NT) stageK_(i + 2, (i & 1) ? K1 : K0);
    if (i + 1 < NT) stageV_(i + 1, (i & 1) ? V0 : V1);
    if (i + 1 < NT) qk((i & 1) ? K0 : K1);
    pv((i & 1) ? V1 : V0, pa0, pa1);
  }

  int b = bh >> 4, h = bh & 15;
#pragma unroll
  for (int r = 0; r < 4; ++r) {
    float i0 = 1.0f / accs0[r];
    float i1 = 1.0f / accs1[r];
#pragma unroll
    for (int qh = 0; qh < 2; ++qh) {
      int srow_o = qt * 128 + wv * 32 + qh * 16 + g * 4 + r;
      float iv = qh ? i1 : i0;
#pragma unroll
      for (int nd = 0; nd < 4; ++nd) {
        int d = nd * 16 + cl;
        float val = (qh ? acc1[nd][r] : acc0[nd][r]) * iv;
        ctx[(((size_t)(b * SEQ + srow_o)) * NHEADS + h) * HDIM + d] = f2bf(val);
      }
    }
  }
}

// ---------------------------------------------------------------- launch
extern "C" void kernel_launch(void* const* d_in, const int* in_sizes, int n_in,
                              void* d_out, int out_size, void* d_ws, size_t ws_size,
                              hipStream_t stream) {
  (void)in_sizes; (void)n_in; (void)out_size; (void)ws_size;
  const float* query = (const float*)d_in[0];
  const float* key_  = (const float*)d_in[1];
  const float* value = (const float*)d_in[2];
  const float* Wq = (const float*)d_in[3];
  const float* bq = (const float*)d_in[4];
  const float* Wk = (const float*)d_in[5];
  const float* bk = (const float*)d_in[6];
  const float* Wv = (const float*)d_in[7];
  const float* bv = (const float*)d_in[8];
  const float* Wo = (const float*)d_in[9];
  const float* bo = (const float*)d_in[10];
  float* out = (float*)d_out;

  unsigned short* w = (unsigned short*)d_ws;
  const size_t NA = (size_t)MROWS * D_MODEL;    // 4M elems
  unsigned short* qs  = w;            // [B,H,S,Dh]
  unsigned short* ks  = qs + NA;
  unsigned short* vtb = ks + NA;      // [B,H,Dh,S]  (written directly by gemm_qkv256)
  unsigned short* cx  = vtb + NA;     // [B,S,D]

  gemm_qkv256<<<dim3(192, 1, 1), 512, 0, stream>>>(query, key_, value, Wq, Wk, Wv,
                                                   bq, bk, bv, qs, ks, vtb);
  attn<<<dim3(32, 16, 1), 256, 0, stream>>>(qs, ks, vtb, cx);
  gemm_out2<<<dim3(256, 1, 1), 512, 0, stream>>>(cx, Wo, bo, out);
}